// Round 13
// baseline (276.585 us; speedup 1.0000x reference)
//
#include <hip/hip_runtime.h>

#define HID 96
#define INDIM 128
#define OUTDIM 10

typedef __attribute__((ext_vector_type(8))) short bf16x8;
typedef __attribute__((ext_vector_type(4))) float f32x4;

__device__ __forceinline__ unsigned short f2bf(float f) {
  unsigned int u = __float_as_uint(f);
  unsigned int r = (u + 0x7FFFu + ((u >> 16) & 1u)) >> 16;  // RNE
  return (unsigned short)r;
}
__device__ __forceinline__ bf16x8 as_bf16x8(uint4 u) {
  union { uint4 a; bf16x8 b; } c; c.a = u; return c.b;
}
__device__ __forceinline__ float bflo(unsigned int u) { return __uint_as_float(u << 16); }
__device__ __forceinline__ float bfhi(unsigned int u) { return __uint_as_float(u & 0xFFFF0000u); }

// ---------------- fused prep: x->bf16 pack | weight->B-frag | zero cnt ----------------
__global__ __launch_bounds__(256) void k_prep(const float* __restrict__ x,
                                              unsigned int* __restrict__ xb, long long xu,
                                              int* __restrict__ cnt, int n, int XB,
                                              const float* __restrict__ encW0,
                                              const float* __restrict__ encW1,
                                              const float* __restrict__ convW,
                                              uint4* __restrict__ wp) {
  int b = blockIdx.x;
  if (b < XB) {
    long long i = (long long)b * 256 + threadIdx.x;
    if (i < xu) {
      float2 v = ((const float2*)x)[i];
      xb[i] = (unsigned int)f2bf(v.x) | ((unsigned int)f2bf(v.y) << 16);
    }
    if (i < n) cnt[i] = 0;
    return;
  }
  int bid = b - XB;
  int lane = threadIdx.x;
  if (lane >= 64) return;
  const float* Wsrc;
  int frag;
  if (bid < 24) { Wsrc = encW0; frag = bid; }                    // K=128: 4 ks * 6 cf
  else if (bid < 42) { Wsrc = encW1; frag = bid - 24; }          // K=96: 3 * 6
  else { int c = bid - 42; Wsrc = convW + (size_t)(c / 18) * HID * HID; frag = c % 18; }
  int ks = frag / 6, cf = frag % 6;
  int col = cf * 16 + (lane & 15);
  int k0 = ks * 32 + (lane >> 4) * 8;
  unsigned int u[4];
#pragma unroll
  for (int p = 0; p < 4; ++p) {
    float lo = Wsrc[(size_t)(k0 + 2 * p) * 96 + col];
    float hi = Wsrc[(size_t)(k0 + 2 * p + 1) * 96 + col];
    u[p] = (unsigned int)f2bf(lo) | ((unsigned int)f2bf(hi) << 16);
  }
  uint4 r; r.x = u[0]; r.y = u[1]; r.z = u[2]; r.w = u[3];
  wp[(size_t)bid * 64 + lane] = r;
}

// ---------------- device bodies ----------------
__device__ __forceinline__ void scanA_body(int blk, const int* __restrict__ cnt, int n,
                                           int* __restrict__ bsum, float* __restrict__ dinv) {
  __shared__ int red[256];
  int t = threadIdx.x;
  int base = blk * 512;
  int v = 0;
  int i0 = base + t, i1 = base + 256 + t;
  if (i0 < n) { int c = cnt[i0]; v += c; dinv[i0] = rsqrtf((float)c + 1.0f); }
  if (i1 < n) { int c = cnt[i1]; v += c; dinv[i1] = rsqrtf((float)c + 1.0f); }
  red[t] = v;
  __syncthreads();
  for (int off = 128; off > 0; off >>= 1) {
    if (t < off) red[t] += red[t + off];
    __syncthreads();
  }
  if (t == 0) bsum[blk] = red[0];
}

template <int KS, bool RELU, bool BIAS, bool SCALE>
__device__ __forceinline__ void gemm_body(int blk, const uint4* __restrict__ Ab,
                                          const uint4* __restrict__ Bp,
                                          const float* __restrict__ bias,
                                          const float* __restrict__ rowscale,
                                          unsigned int* __restrict__ outB, int M) {
  int t = threadIdx.x, wid = t >> 6, lane = t & 63;
  int rowbase = blk * 64 + wid * 16;
  int arow = rowbase + (lane & 15);
  if (arow >= M) arow = M - 1;
  constexpr int RU4 = KS * 4;

  f32x4 acc[6];
#pragma unroll
  for (int cf = 0; cf < 6; ++cf)
#pragma unroll
    for (int j = 0; j < 4; ++j) acc[cf][j] = 0.f;

#pragma unroll
  for (int ks = 0; ks < KS; ++ks) {
    uint4 a = Ab[(size_t)arow * RU4 + ks * 4 + (lane >> 4)];
    bf16x8 af = as_bf16x8(a);
#pragma unroll
    for (int cf = 0; cf < 6; ++cf) {
      uint4 b = Bp[(size_t)(ks * 6 + cf) * 64 + lane];
      acc[cf] = __builtin_amdgcn_mfma_f32_16x16x32_bf16(af, as_bf16x8(b), acc[cf], 0, 0, 0);
    }
  }

  int rows[4]; float rs[4];
#pragma unroll
  for (int i = 0; i < 4; ++i) {
    rows[i] = rowbase + (lane >> 4) * 4 + i;
    int cr = rows[i] < M ? rows[i] : M - 1;
    rs[i] = SCALE ? rowscale[cr] : 1.f;
  }
#pragma unroll
  for (int cf = 0; cf < 6; ++cf) {
    int col = cf * 16 + (lane & 15);
    float bv = BIAS ? bias[col] : 0.f;
#pragma unroll
    for (int i = 0; i < 4; ++i) {
      float v = acc[cf][i] + bv;
      if (RELU) v = fmaxf(v, 0.f);
      v *= rs[i];
      float p = __shfl_xor(v, 1);
      if (!(lane & 1) && rows[i] < M) {
        unsigned int u = (unsigned int)f2bf(v) | ((unsigned int)f2bf(p) << 16);
        outB[(size_t)rows[i] * 48 + cf * 8 + ((lane & 15) >> 1)] = u;
      }
    }
  }
}

// ---------------- fused kernels: independent halves by block range ----------------
__global__ __launch_bounds__(256) void k_count_enc1(
    const int4* __restrict__ dst4, int E4, int* __restrict__ cnt, int* __restrict__ rank,
    int CB, const uint4* __restrict__ Ab, const uint4* __restrict__ Bp,
    const float* __restrict__ bias, unsigned int* __restrict__ outB, int M) {
  int b = blockIdx.x;
  if (b < CB) {
    int i = b * 256 + threadIdx.x;
    if (i >= E4) return;
    int4 d = dst4[i];
    int r0 = atomicAdd(&cnt[d.x], 1);
    int r1 = atomicAdd(&cnt[d.y], 1);
    int r2 = atomicAdd(&cnt[d.z], 1);
    int r3 = atomicAdd(&cnt[d.w], 1);
    ((int4*)rank)[i] = make_int4(r0, r1, r2, r3);
  } else {
    gemm_body<4, true, true, false>(b - CB, Ab, Bp, bias, nullptr, outB, M);
  }
}

__global__ __launch_bounds__(256) void k_scanA_enc2(
    const int* __restrict__ cnt, int n, int* __restrict__ bsum, float* __restrict__ dinv,
    int SB, const uint4* __restrict__ Ab, const uint4* __restrict__ Bp,
    const float* __restrict__ bias, unsigned int* __restrict__ outB, int M) {
  int b = blockIdx.x;
  if (b < SB) scanA_body(b, cnt, n, bsum, dinv);
  else gemm_body<3, false, true, false>(b - SB, Ab, Bp, bias, nullptr, outB, M);
}

// scanC with inline block-offset reduction
__global__ __launch_bounds__(256) void k_scanC(const int* __restrict__ cnt, int n,
                                               const int* __restrict__ bsum, int nb,
                                               int* __restrict__ rowp, int Etot) {
  __shared__ int s[256];
  int b = blockIdx.x, t = threadIdx.x;
  int v0 = (t < b && t < nb) ? bsum[t] : 0;
  s[t] = v0;
  __syncthreads();
  for (int off = 128; off > 0; off >>= 1) {
    if (t < off) s[t] += s[t + off];
    __syncthreads();
  }
  int boff = s[0];
  __syncthreads();

  int base = b * 512;
  int i0 = base + 2 * t, i1 = i0 + 1;
  int c0 = (i0 < n) ? cnt[i0] : 0;
  int c1 = (i1 < n) ? cnt[i1] : 0;
  int pair = c0 + c1;
  s[t] = pair;
  __syncthreads();
  for (int off = 1; off < 256; off <<= 1) {
    int u = (t >= off) ? s[t - off] : 0;
    __syncthreads();
    s[t] += u;
    __syncthreads();
  }
  int excl = s[t] - pair + boff;
  if (i0 < n) rowp[i0] = excl;
  if (i1 < n) rowp[i1] = excl + c0;
  if (b == 0 && t == 0) rowp[n] = Etot;
}

// fill || conv gemm l=0
__global__ __launch_bounds__(256) void k_fill_conv(
    const int4* __restrict__ src4, const int4* __restrict__ dst4,
    const int4* __restrict__ rank4, int E4, const int* __restrict__ rowp,
    int* __restrict__ csr, int FB, const uint4* __restrict__ Ab,
    const uint4* __restrict__ Bp, const float* __restrict__ rowscale,
    unsigned int* __restrict__ outB, int M) {
  int b = blockIdx.x;
  if (b < FB) {
    int i = b * 256 + threadIdx.x;
    if (i >= E4) return;
    int4 s = src4[i];
    int4 d = dst4[i];
    int4 r = rank4[i];
    csr[rowp[d.x] + r.x] = s.x;
    csr[rowp[d.y] + r.y] = s.y;
    csr[rowp[d.z] + r.z] = s.z;
    csr[rowp[d.w] + r.w] = s.w;
  } else {
    gemm_body<3, false, false, true>(b - FB, Ab, Bp, nullptr, rowscale, outB, M);
  }
}

// standalone gemm for conv layers >= 1
template <int KS, bool RELU, bool BIAS, bool SCALE>
__global__ __launch_bounds__(256) void mfma_gemm(const uint4* __restrict__ Ab,
                                                 const uint4* __restrict__ Bp,
                                                 const float* __restrict__ bias,
                                                 const float* __restrict__ rowscale,
                                                 unsigned int* __restrict__ outB, int M) {
  gemm_body<KS, RELU, BIAS, SCALE>(blockIdx.x, Ab, Bp, bias, rowscale, outB, M);
}

// ---------------- GCN aggregation: 2 nodes/wave, 32 gathers in flight ----------------
// Both nodes' 16-edge groups are STAGED (all 32 loads issued) before accumulation.
// Group-partial summation order matches previous kernel (absmax-stable).
__global__ __launch_bounds__(256) void k_agg(const unsigned int* __restrict__ hw_s,
                                             const int* __restrict__ rowp,
                                             const int* __restrict__ csr,
                                             const float* __restrict__ dinv,
                                             const float* __restrict__ bias,
                                             unsigned int* __restrict__ outB, int n) {
  int wave = threadIdx.x >> 6;
  int lane = threadIdx.x & 63;
  int nA = blockIdx.x * 8 + wave * 2;
  if (nA >= n) return;
  int nB = nA + 1;
  int cB = nB < n ? nB : nA;
  bool act = lane < 48;
  int li = act ? lane : 0;
  int eA = rowp[nA], endA = rowp[nA + 1];
  int eB = rowp[cB], endB = rowp[cB + 1];
  int lastA = endA > 0 ? endA - 1 : 0;
  int lastB = endB > 0 ? endB - 1 : 0;
  float a0 = 0.f, a1 = 0.f, b0 = 0.f, b1 = 0.f;

  while (eA < endA || eB < endB) {
    unsigned int uA[16], uB[16];
    float mA[16], mB[16];
#pragma unroll
    for (int j = 0; j < 16; ++j) {
      int ia = eA + j;
      bool ok = ia < endA;
      int ci = csr[ok ? ia : lastA];
      uA[j] = hw_s[(size_t)ci * 48 + li];
      mA[j] = ok ? 1.f : 0.f;
    }
#pragma unroll
    for (int j = 0; j < 16; ++j) {
      int ib = eB + j;
      bool ok = ib < endB;
      int ci = csr[ok ? ib : lastB];
      uB[j] = hw_s[(size_t)ci * 48 + li];
      mB[j] = ok ? 1.f : 0.f;
    }
    float pa0 = 0.f, pa1 = 0.f, pb0 = 0.f, pb1 = 0.f;
#pragma unroll
    for (int j = 0; j < 16; ++j) { pa0 += mA[j] * bflo(uA[j]); pa1 += mA[j] * bfhi(uA[j]); }
#pragma unroll
    for (int j = 0; j < 16; ++j) { pb0 += mB[j] * bflo(uB[j]); pb1 += mB[j] * bfhi(uB[j]); }
    a0 += pa0; a1 += pa1; b0 += pb0; b1 += pb1;
    eA += 16; eB += 16;
  }

  if (act) {
    float2 bv = ((const float2*)bias)[li];
    float diA = dinv[nA];
    unsigned int usA = hw_s[(size_t)nA * 48 + li];
    float r0 = fmaxf(diA * (a0 + bflo(usA)) + bv.x, 0.f);
    float r1 = fmaxf(diA * (a1 + bfhi(usA)) + bv.y, 0.f);
    outB[(size_t)nA * 48 + li] = (unsigned int)f2bf(r0) | ((unsigned int)f2bf(r1) << 16);
    if (nB < n) {
      float diB = dinv[nB];
      unsigned int usB = hw_s[(size_t)nB * 48 + li];
      float s0 = fmaxf(diB * (b0 + bflo(usB)) + bv.x, 0.f);
      float s1 = fmaxf(diB * (b1 + bfhi(usB)) + bv.y, 0.f);
      outB[(size_t)nB * 48 + li] = (unsigned int)f2bf(s0) | ((unsigned int)f2bf(s1) << 16);
    }
  }
}

// ---------------- fused head: global add pool + decoder MLP ----------------
__global__ __launch_bounds__(256) void k_head(const unsigned int* __restrict__ hb,
                                              const int* __restrict__ batch, int n,
                                              const float* __restrict__ W0,
                                              const float* __restrict__ b0,
                                              const float* __restrict__ W1,
                                              const float* __restrict__ b1,
                                              float* __restrict__ out) {
  __shared__ float w0L[HID * HID];  // 36 KB
  __shared__ float red[4][HID];
  __shared__ float g1L[HID];
  __shared__ float g2L[HID];
  int gr = blockIdx.x;
  int t = threadIdx.x, wv = t >> 6, lane = t & 63;

  for (int i = t; i < HID * HID / 4; i += 256) ((float4*)w0L)[i] = ((const float4*)W0)[i];

  int lo = 0, hi = n;
  while (lo < hi) { int m = (lo + hi) >> 1; if (batch[m] < gr) lo = m + 1; else hi = m; }
  int start = lo;
  hi = n;
  while (lo < hi) { int m = (lo + hi) >> 1; if (batch[m] < gr + 1) lo = m + 1; else hi = m; }
  int end = lo;

  if (lane < 48) {
    float s0 = 0.f, s1 = 0.f;
    for (int i = start + wv; i < end; i += 4) {
      unsigned int u = hb[(size_t)i * 48 + lane];
      s0 += bflo(u);
      s1 += bfhi(u);
    }
    red[wv][2 * lane] = s0;
    red[wv][2 * lane + 1] = s1;
  }
  __syncthreads();
  if (t < HID) g1L[t] = red[0][t] + red[1][t] + red[2][t] + red[3][t];
  __syncthreads();
  if (t < HID) {
    float a = b0[t];
    for (int k = 0; k < HID; ++k) a += g1L[k] * w0L[k * HID + t];
    g2L[t] = fmaxf(a, 0.f);
  }
  __syncthreads();
  if (t < OUTDIM) {
    float a = b1[t];
    for (int k = 0; k < HID; ++k) a += g2L[k] * W1[k * OUTDIM + t];
    out[(size_t)gr * OUTDIM + t] = a;
  }
}

extern "C" void kernel_launch(void* const* d_in, const int* in_sizes, int n_in,
                              void* d_out, int out_size, void* d_ws, size_t ws_size,
                              hipStream_t stream) {
  const float* x     = (const float*)d_in[0];
  const int*   ei    = (const int*)d_in[1];
  const int*   batch = (const int*)d_in[2];
  const float* encW0 = (const float*)d_in[3];
  const float* encb0 = (const float*)d_in[4];
  const float* encW1 = (const float*)d_in[5];
  const float* encb1 = (const float*)d_in[6];
  const float* convW = (const float*)d_in[7];
  const float* convb = (const float*)d_in[8];
  const float* decW0 = (const float*)d_in[9];
  const float* decb0 = (const float*)d_in[10];
  const float* decW1 = (const float*)d_in[11];
  const float* decb1 = (const float*)d_in[12];
  float* out = (float*)d_out;

  int n  = in_sizes[0] / INDIM;
  int E  = in_sizes[1] / 2;
  int G  = out_size / OUTDIM;
  int NC = in_sizes[7] / (HID * HID);

  const int* srcI = ei;
  const int* dstI = ei + E;

  char* w = (char*)d_ws;
  auto alloc = [&](size_t bytes) {
    char* p = w;
    w += (bytes + 255) & ~(size_t)255;
    return p;
  };
  unsigned int* xb  = (unsigned int*)alloc((size_t)n * (INDIM / 2) * 4);
  unsigned int* hbA = (unsigned int*)alloc((size_t)n * 48 * 4);
  unsigned int* hbB = (unsigned int*)alloc((size_t)n * 48 * 4);
  unsigned int* hwb = (unsigned int*)alloc((size_t)n * 48 * 4);
  uint4* wp   = (uint4*)alloc((size_t)(42 + NC * 18) * 64 * 16);
  int*   cnt   = (int*)alloc((size_t)n * 4);
  int*   rankb = (int*)alloc((size_t)E * 4);
  int*   rowp  = (int*)alloc((size_t)(n + 1) * 4);
  int*   csr   = (int*)alloc((size_t)E * 4);
  float* dinv  = (float*)alloc((size_t)n * 4);
  int*   bsum  = (int*)alloc(256 * 4);

  long long xu = (long long)n * (INDIM / 2);
  int XB = (int)((xu + 255) / 256);
  int WB = 42 + NC * 18;
  k_prep<<<XB + WB, 256, 0, stream>>>(x, xb, xu, cnt, n, XB, encW0, encW1, convW, wp);

  int E4 = E / 4;                 // E = 800000, divisible by 4
  int eb4 = (E4 + 255) / 256;
  int nb = (n + 511) / 512;
  int gb = (n + 63) / 64;

  // count (4 edges/thread int4) || encoder gemm1
  k_count_enc1<<<eb4 + gb, 256, 0, stream>>>((const int4*)dstI, E4, cnt, rankb, eb4,
                                             (const uint4*)xb, wp, encb0, hbA, n);
  // scanA(+dinv) || encoder gemm2
  k_scanA_enc2<<<nb + gb, 256, 0, stream>>>(cnt, n, bsum, dinv, nb,
                                            (const uint4*)hbA, wp + (size_t)24 * 64,
                                            encb1, hbB, n);
  k_scanC<<<nb, 256, 0, stream>>>(cnt, n, bsum, nb, rowp, E);
  // fill || conv gemm l=0 (hwb0 = (h0 @ W0) * dinv)
  k_fill_conv<<<eb4 + gb, 256, 0, stream>>>((const int4*)srcI, (const int4*)dstI,
                                            (const int4*)rankb, E4, rowp, csr, eb4,
                                            (const uint4*)hbB, wp + (size_t)42 * 64,
                                            dinv, hwb, n);
  int ab = (n + 7) / 8;
  k_agg<<<ab, 256, 0, stream>>>(hwb, rowp, csr, dinv, convb, hbB, n);

  for (int l = 1; l < NC; ++l) {
    mfma_gemm<3, false, false, true><<<gb, 256, 0, stream>>>(
        (const uint4*)hbB, wp + (size_t)(42 + l * 18) * 64, nullptr, dinv, hwb, n);
    k_agg<<<ab, 256, 0, stream>>>(hwb, rowp, csr, dinv,
                                  convb + (size_t)l * HID, hbB, n);
  }
  k_head<<<G, 256, 0, stream>>>(hbB, batch, n, decW0, decb0, decW1, decb1, out);
}

// Round 14
// 247.952 us; speedup vs baseline: 1.1155x; 1.1155x over previous
//
#include <hip/hip_runtime.h>

#define HID 96
#define INDIM 128
#define OUTDIM 10

typedef __attribute__((ext_vector_type(8))) short bf16x8;
typedef __attribute__((ext_vector_type(4))) float f32x4;

__device__ __forceinline__ unsigned short f2bf(float f) {
  unsigned int u = __float_as_uint(f);
  unsigned int r = (u + 0x7FFFu + ((u >> 16) & 1u)) >> 16;  // RNE
  return (unsigned short)r;
}
__device__ __forceinline__ bf16x8 as_bf16x8(uint4 u) {
  union { uint4 a; bf16x8 b; } c; c.a = u; return c.b;
}
__device__ __forceinline__ float bflo(unsigned int u) { return __uint_as_float(u << 16); }
__device__ __forceinline__ float bfhi(unsigned int u) { return __uint_as_float(u & 0xFFFF0000u); }

// ---------------- fused prep: x->bf16 pack | weight->B-frag | zero cnt ----------------
__global__ __launch_bounds__(256) void k_prep(const float* __restrict__ x,
                                              unsigned int* __restrict__ xb, long long xu,
                                              int* __restrict__ cnt, int n, int XB,
                                              const float* __restrict__ encW0,
                                              const float* __restrict__ encW1,
                                              const float* __restrict__ convW,
                                              uint4* __restrict__ wp) {
  int b = blockIdx.x;
  if (b < XB) {
    long long i = (long long)b * 256 + threadIdx.x;
    if (i < xu) {
      float2 v = ((const float2*)x)[i];
      xb[i] = (unsigned int)f2bf(v.x) | ((unsigned int)f2bf(v.y) << 16);
    }
    if (i < n) cnt[i] = 0;
    return;
  }
  int bid = b - XB;
  int lane = threadIdx.x;
  if (lane >= 64) return;
  const float* Wsrc;
  int frag;
  if (bid < 24) { Wsrc = encW0; frag = bid; }                    // K=128: 4 ks * 6 cf
  else if (bid < 42) { Wsrc = encW1; frag = bid - 24; }          // K=96: 3 * 6
  else { int c = bid - 42; Wsrc = convW + (size_t)(c / 18) * HID * HID; frag = c % 18; }
  int ks = frag / 6, cf = frag % 6;
  int col = cf * 16 + (lane & 15);
  int k0 = ks * 32 + (lane >> 4) * 8;
  unsigned int u[4];
#pragma unroll
  for (int p = 0; p < 4; ++p) {
    float lo = Wsrc[(size_t)(k0 + 2 * p) * 96 + col];
    float hi = Wsrc[(size_t)(k0 + 2 * p + 1) * 96 + col];
    u[p] = (unsigned int)f2bf(lo) | ((unsigned int)f2bf(hi) << 16);
  }
  uint4 r; r.x = u[0]; r.y = u[1]; r.z = u[2]; r.w = u[3];
  wp[(size_t)bid * 64 + lane] = r;
}

// ---------------- device bodies ----------------
__device__ __forceinline__ void scanA_body(int blk, const int* __restrict__ cnt, int n,
                                           int* __restrict__ bsum, float* __restrict__ dinv) {
  __shared__ int red[256];
  int t = threadIdx.x;
  int base = blk * 512;
  int v = 0;
  int i0 = base + t, i1 = base + 256 + t;
  if (i0 < n) { int c = cnt[i0]; v += c; dinv[i0] = rsqrtf((float)c + 1.0f); }
  if (i1 < n) { int c = cnt[i1]; v += c; dinv[i1] = rsqrtf((float)c + 1.0f); }
  red[t] = v;
  __syncthreads();
  for (int off = 128; off > 0; off >>= 1) {
    if (t < off) red[t] += red[t + off];
    __syncthreads();
  }
  if (t == 0) bsum[blk] = red[0];
}

template <int KS, bool RELU, bool BIAS, bool SCALE>
__device__ __forceinline__ void gemm_body(int blk, const uint4* __restrict__ Ab,
                                          const uint4* __restrict__ Bp,
                                          const float* __restrict__ bias,
                                          const float* __restrict__ rowscale,
                                          unsigned int* __restrict__ outB, int M) {
  int t = threadIdx.x, wid = t >> 6, lane = t & 63;
  int rowbase = blk * 64 + wid * 16;
  int arow = rowbase + (lane & 15);
  if (arow >= M) arow = M - 1;
  constexpr int RU4 = KS * 4;

  f32x4 acc[6];
#pragma unroll
  for (int cf = 0; cf < 6; ++cf)
#pragma unroll
    for (int j = 0; j < 4; ++j) acc[cf][j] = 0.f;

#pragma unroll
  for (int ks = 0; ks < KS; ++ks) {
    uint4 a = Ab[(size_t)arow * RU4 + ks * 4 + (lane >> 4)];
    bf16x8 af = as_bf16x8(a);
#pragma unroll
    for (int cf = 0; cf < 6; ++cf) {
      uint4 b = Bp[(size_t)(ks * 6 + cf) * 64 + lane];
      acc[cf] = __builtin_amdgcn_mfma_f32_16x16x32_bf16(af, as_bf16x8(b), acc[cf], 0, 0, 0);
    }
  }

  int rows[4]; float rs[4];
#pragma unroll
  for (int i = 0; i < 4; ++i) {
    rows[i] = rowbase + (lane >> 4) * 4 + i;
    int cr = rows[i] < M ? rows[i] : M - 1;
    rs[i] = SCALE ? rowscale[cr] : 1.f;
  }
#pragma unroll
  for (int cf = 0; cf < 6; ++cf) {
    int col = cf * 16 + (lane & 15);
    float bv = BIAS ? bias[col] : 0.f;
#pragma unroll
    for (int i = 0; i < 4; ++i) {
      float v = acc[cf][i] + bv;
      if (RELU) v = fmaxf(v, 0.f);
      v *= rs[i];
      float p = __shfl_xor(v, 1);
      if (!(lane & 1) && rows[i] < M) {
        unsigned int u = (unsigned int)f2bf(v) | ((unsigned int)f2bf(p) << 16);
        outB[(size_t)rows[i] * 48 + cf * 8 + ((lane & 15) >> 1)] = u;
      }
    }
  }
}

// ---------------- fused kernels: independent halves by block range ----------------
__global__ __launch_bounds__(256) void k_count_enc1(
    const int4* __restrict__ dst4, int E4, int* __restrict__ cnt, int* __restrict__ rank,
    int CB, const uint4* __restrict__ Ab, const uint4* __restrict__ Bp,
    const float* __restrict__ bias, unsigned int* __restrict__ outB, int M) {
  int b = blockIdx.x;
  if (b < CB) {
    int i = b * 256 + threadIdx.x;
    if (i >= E4) return;
    int4 d = dst4[i];
    int r0 = atomicAdd(&cnt[d.x], 1);
    int r1 = atomicAdd(&cnt[d.y], 1);
    int r2 = atomicAdd(&cnt[d.z], 1);
    int r3 = atomicAdd(&cnt[d.w], 1);
    ((int4*)rank)[i] = make_int4(r0, r1, r2, r3);
  } else {
    gemm_body<4, true, true, false>(b - CB, Ab, Bp, bias, nullptr, outB, M);
  }
}

__global__ __launch_bounds__(256) void k_scanA_enc2(
    const int* __restrict__ cnt, int n, int* __restrict__ bsum, float* __restrict__ dinv,
    int SB, const uint4* __restrict__ Ab, const uint4* __restrict__ Bp,
    const float* __restrict__ bias, unsigned int* __restrict__ outB, int M) {
  int b = blockIdx.x;
  if (b < SB) scanA_body(b, cnt, n, bsum, dinv);
  else gemm_body<3, false, true, false>(b - SB, Ab, Bp, bias, nullptr, outB, M);
}

// scanC with inline block-offset reduction
__global__ __launch_bounds__(256) void k_scanC(const int* __restrict__ cnt, int n,
                                               const int* __restrict__ bsum, int nb,
                                               int* __restrict__ rowp, int Etot) {
  __shared__ int s[256];
  int b = blockIdx.x, t = threadIdx.x;
  int v0 = (t < b && t < nb) ? bsum[t] : 0;
  s[t] = v0;
  __syncthreads();
  for (int off = 128; off > 0; off >>= 1) {
    if (t < off) s[t] += s[t + off];
    __syncthreads();
  }
  int boff = s[0];
  __syncthreads();

  int base = b * 512;
  int i0 = base + 2 * t, i1 = i0 + 1;
  int c0 = (i0 < n) ? cnt[i0] : 0;
  int c1 = (i1 < n) ? cnt[i1] : 0;
  int pair = c0 + c1;
  s[t] = pair;
  __syncthreads();
  for (int off = 1; off < 256; off <<= 1) {
    int u = (t >= off) ? s[t - off] : 0;
    __syncthreads();
    s[t] += u;
    __syncthreads();
  }
  int excl = s[t] - pair + boff;
  if (i0 < n) rowp[i0] = excl;
  if (i1 < n) rowp[i1] = excl + c0;
  if (b == 0 && t == 0) rowp[n] = Etot;
}

// fill || conv gemm l=0
__global__ __launch_bounds__(256) void k_fill_conv(
    const int4* __restrict__ src4, const int4* __restrict__ dst4,
    const int4* __restrict__ rank4, int E4, const int* __restrict__ rowp,
    int* __restrict__ csr, int FB, const uint4* __restrict__ Ab,
    const uint4* __restrict__ Bp, const float* __restrict__ rowscale,
    unsigned int* __restrict__ outB, int M) {
  int b = blockIdx.x;
  if (b < FB) {
    int i = b * 256 + threadIdx.x;
    if (i >= E4) return;
    int4 s = src4[i];
    int4 d = dst4[i];
    int4 r = rank4[i];
    csr[rowp[d.x] + r.x] = s.x;
    csr[rowp[d.y] + r.y] = s.y;
    csr[rowp[d.z] + r.z] = s.z;
    csr[rowp[d.w] + r.w] = s.w;
  } else {
    gemm_body<3, false, false, true>(b - FB, Ab, Bp, nullptr, rowscale, outB, M);
  }
}

// standalone gemm for conv layers >= 1
template <int KS, bool RELU, bool BIAS, bool SCALE>
__global__ __launch_bounds__(256) void mfma_gemm(const uint4* __restrict__ Ab,
                                                 const uint4* __restrict__ Bp,
                                                 const float* __restrict__ bias,
                                                 const float* __restrict__ rowscale,
                                                 unsigned int* __restrict__ outB, int M) {
  gemm_body<KS, RELU, BIAS, SCALE>(blockIdx.x, Ab, Bp, bias, rowscale, outB, M);
}

// ---------------- GCN aggregation (bf16 gather, f32 accumulate, bf16 out) ----------------
// 16-deep unrolled gather; remainder handled by ONE predicated 16-group (clamped index).
__global__ __launch_bounds__(256) void k_agg(const unsigned int* __restrict__ hw_s,
                                             const int* __restrict__ rowp,
                                             const int* __restrict__ csr,
                                             const float* __restrict__ dinv,
                                             const float* __restrict__ bias,
                                             unsigned int* __restrict__ outB, int n) {
  int wave = threadIdx.x >> 6;
  int lane = threadIdx.x & 63;
  int node = blockIdx.x * 4 + wave;
  if (node >= n) return;
  int beg = rowp[node], end = rowp[node + 1];
  float acc0 = 0.f, acc1 = 0.f;
  bool act = lane < 48;
  int li = act ? lane : 0;
  int e = beg;
  for (; e + 16 <= end; e += 16) {
    unsigned int uu[16];
#pragma unroll
    for (int j = 0; j < 16; ++j) uu[j] = hw_s[(size_t)csr[e + j] * 48 + li];
    float a0 = 0.f, a1 = 0.f;
#pragma unroll
    for (int j = 0; j < 16; ++j) { a0 += bflo(uu[j]); a1 += bfhi(uu[j]); }
    acc0 += a0; acc1 += a1;
  }
  if (e < end) {
    unsigned int uu[16]; float m[16];
#pragma unroll
    for (int j = 0; j < 16; ++j) {
      int idx = e + j;
      bool ok = idx < end;
      int ci = csr[ok ? idx : end - 1];
      uu[j] = hw_s[(size_t)ci * 48 + li];
      m[j] = ok ? 1.f : 0.f;
    }
    float a0 = 0.f, a1 = 0.f;
#pragma unroll
    for (int j = 0; j < 16; ++j) { a0 += m[j] * bflo(uu[j]); a1 += m[j] * bfhi(uu[j]); }
    acc0 += a0; acc1 += a1;
  }
  if (act) {
    float di = dinv[node];
    unsigned int us = hw_s[(size_t)node * 48 + li];
    float2 bv = ((const float2*)bias)[li];
    float r0 = fmaxf(di * (acc0 + bflo(us)) + bv.x, 0.f);
    float r1 = fmaxf(di * (acc1 + bfhi(us)) + bv.y, 0.f);
    outB[(size_t)node * 48 + li] = (unsigned int)f2bf(r0) | ((unsigned int)f2bf(r1) << 16);
  }
}

// ---------------- fused head: global add pool + decoder MLP ----------------
__global__ __launch_bounds__(256) void k_head(const unsigned int* __restrict__ hb,
                                              const int* __restrict__ batch, int n,
                                              const float* __restrict__ W0,
                                              const float* __restrict__ b0,
                                              const float* __restrict__ W1,
                                              const float* __restrict__ b1,
                                              float* __restrict__ out) {
  __shared__ float w0L[HID * HID];  // 36 KB
  __shared__ float red[4][HID];
  __shared__ float g1L[HID];
  __shared__ float g2L[HID];
  int gr = blockIdx.x;
  int t = threadIdx.x, wv = t >> 6, lane = t & 63;

  for (int i = t; i < HID * HID / 4; i += 256) ((float4*)w0L)[i] = ((const float4*)W0)[i];

  int lo = 0, hi = n;
  while (lo < hi) { int m = (lo + hi) >> 1; if (batch[m] < gr) lo = m + 1; else hi = m; }
  int start = lo;
  hi = n;
  while (lo < hi) { int m = (lo + hi) >> 1; if (batch[m] < gr + 1) lo = m + 1; else hi = m; }
  int end = lo;

  if (lane < 48) {
    float s0 = 0.f, s1 = 0.f;
    for (int i = start + wv; i < end; i += 4) {
      unsigned int u = hb[(size_t)i * 48 + lane];
      s0 += bflo(u);
      s1 += bfhi(u);
    }
    red[wv][2 * lane] = s0;
    red[wv][2 * lane + 1] = s1;
  }
  __syncthreads();
  if (t < HID) g1L[t] = red[0][t] + red[1][t] + red[2][t] + red[3][t];
  __syncthreads();
  if (t < HID) {
    float a = b0[t];
    for (int k = 0; k < HID; ++k) a += g1L[k] * w0L[k * HID + t];
    g2L[t] = fmaxf(a, 0.f);
  }
  __syncthreads();
  if (t < OUTDIM) {
    float a = b1[t];
    for (int k = 0; k < HID; ++k) a += g2L[k] * W1[k * OUTDIM + t];
    out[(size_t)gr * OUTDIM + t] = a;
  }
}

extern "C" void kernel_launch(void* const* d_in, const int* in_sizes, int n_in,
                              void* d_out, int out_size, void* d_ws, size_t ws_size,
                              hipStream_t stream) {
  const float* x     = (const float*)d_in[0];
  const int*   ei    = (const int*)d_in[1];
  const int*   batch = (const int*)d_in[2];
  const float* encW0 = (const float*)d_in[3];
  const float* encb0 = (const float*)d_in[4];
  const float* encW1 = (const float*)d_in[5];
  const float* encb1 = (const float*)d_in[6];
  const float* convW = (const float*)d_in[7];
  const float* convb = (const float*)d_in[8];
  const float* decW0 = (const float*)d_in[9];
  const float* decb0 = (const float*)d_in[10];
  const float* decW1 = (const float*)d_in[11];
  const float* decb1 = (const float*)d_in[12];
  float* out = (float*)d_out;

  int n  = in_sizes[0] / INDIM;
  int E  = in_sizes[1] / 2;
  int G  = out_size / OUTDIM;
  int NC = in_sizes[7] / (HID * HID);

  const int* srcI = ei;
  const int* dstI = ei + E;

  char* w = (char*)d_ws;
  auto alloc = [&](size_t bytes) {
    char* p = w;
    w += (bytes + 255) & ~(size_t)255;
    return p;
  };
  unsigned int* xb  = (unsigned int*)alloc((size_t)n * (INDIM / 2) * 4);
  unsigned int* hbA = (unsigned int*)alloc((size_t)n * 48 * 4);
  unsigned int* hbB = (unsigned int*)alloc((size_t)n * 48 * 4);
  unsigned int* hwb = (unsigned int*)alloc((size_t)n * 48 * 4);
  uint4* wp   = (uint4*)alloc((size_t)(42 + NC * 18) * 64 * 16);
  int*   cnt   = (int*)alloc((size_t)n * 4);
  int*   rankb = (int*)alloc((size_t)E * 4);
  int*   rowp  = (int*)alloc((size_t)(n + 1) * 4);
  int*   csr   = (int*)alloc((size_t)E * 4);
  float* dinv  = (float*)alloc((size_t)n * 4);
  int*   bsum  = (int*)alloc(256 * 4);

  long long xu = (long long)n * (INDIM / 2);
  int XB = (int)((xu + 255) / 256);
  int WB = 42 + NC * 18;
  k_prep<<<XB + WB, 256, 0, stream>>>(x, xb, xu, cnt, n, XB, encW0, encW1, convW, wp);

  int E4 = E / 4;                 // E = 800000, divisible by 4
  int eb4 = (E4 + 255) / 256;
  int nb = (n + 511) / 512;
  int gb = (n + 63) / 64;

  // count (4 edges/thread int4) || encoder gemm1
  k_count_enc1<<<eb4 + gb, 256, 0, stream>>>((const int4*)dstI, E4, cnt, rankb, eb4,
                                             (const uint4*)xb, wp, encb0, hbA, n);
  // scanA(+dinv) || encoder gemm2
  k_scanA_enc2<<<nb + gb, 256, 0, stream>>>(cnt, n, bsum, dinv, nb,
                                            (const uint4*)hbA, wp + (size_t)24 * 64,
                                            encb1, hbB, n);
  k_scanC<<<nb, 256, 0, stream>>>(cnt, n, bsum, nb, rowp, E);
  // fill || conv gemm l=0 (hwb0 = (h0 @ W0) * dinv)
  k_fill_conv<<<eb4 + gb, 256, 0, stream>>>((const int4*)srcI, (const int4*)dstI,
                                            (const int4*)rankb, E4, rowp, csr, eb4,
                                            (const uint4*)hbB, wp + (size_t)42 * 64,
                                            dinv, hwb, n);
  k_agg<<<(n + 3) / 4, 256, 0, stream>>>(hwb, rowp, csr, dinv, convb, hbB, n);

  for (int l = 1; l < NC; ++l) {
    mfma_gemm<3, false, false, true><<<gb, 256, 0, stream>>>(
        (const uint4*)hbB, wp + (size_t)(42 + l * 18) * 64, nullptr, dinv, hwb, n);
    k_agg<<<(n + 3) / 4, 256, 0, stream>>>(hwb, rowp, csr, dinv,
                                           convb + (size_t)l * HID, hbB, n);
  }
  k_head<<<G, 256, 0, stream>>>(hbB, batch, n, decW0, decb0, decW1, decb1, out);
}